// Round 1
// 152.012 us; speedup vs baseline: 1.0064x; 1.0064x over previous
//
#include <hip/hip_runtime.h>
#include <stdint.h>

typedef short short8 __attribute__((ext_vector_type(8)));
typedef short short4_t __attribute__((ext_vector_type(4)));
typedef float f32x4 __attribute__((ext_vector_type(4)));

__device__ __forceinline__ float bf2f(unsigned short u) {
    union { unsigned int i; float f; } v; v.i = ((unsigned int)u) << 16; return v.f;
}
// round-half-up bf16 (max 0.5 ulp, 2 VALU ops)
__device__ __forceinline__ unsigned short f2bf(float f) {
    union { float f; unsigned int i; } v; v.f = f;
    return (unsigned short)((v.i + 0x8000u) >> 16);
}

// ---------------- kernel A: fused x->bf16 hi/lo + weight transpose ---------
__global__ __launch_bounds__(256) void k_pre(const float* __restrict__ x,
                                             const float* __restrict__ Wf,
                                             const float* __restrict__ Wg,
                                             const float* __restrict__ Wh,
                                             unsigned short* __restrict__ xh,
                                             unsigned short* __restrict__ xl,
                                             unsigned short* __restrict__ wTh,
                                             unsigned short* __restrict__ wTl) {
    if (blockIdx.x < 2048) {
        int gid = blockIdx.x * 256 + threadIdx.x;   // 8 elems each
        const float* src = x + (size_t)gid * 8;
        f32x4 a0 = *(const f32x4*)src;
        f32x4 a1 = *(const f32x4*)(src + 4);
        short8 sh, sl;
#pragma unroll
        for (int j = 0; j < 4; ++j) {
            unsigned short h0 = f2bf(a0[j]);
            sh[j] = (short)h0; sl[j] = (short)f2bf(a0[j] - bf2f(h0));
            unsigned short h1 = f2bf(a1[j]);
            sh[4 + j] = (short)h1; sl[4 + j] = (short)f2bf(a1[j] - bf2f(h1));
        }
        *(short8*)&xh[(size_t)gid * 8] = sh;
        *(short8*)&xl[(size_t)gid * 8] = sl;
    } else {
        int col = blockIdx.x - 2048;   // 0..319
        int k = threadIdx.x;           // 0..255
        float v;
        if (col < 32) v = Wf[k * 32 + col];
        else if (col < 64) v = Wg[k * 32 + (col - 32)];
        else v = Wh[k * 256 + (col - 64)];
        unsigned short h = f2bf(v);
        wTh[col * 256 + k] = h;
        if (col < 64) wTl[col * 256 + k] = f2bf(v - bf2f(h));
    }
}

// ---------------- kernel B: fused projections (grid 256 x 5) ---------------
// Outputs in FRAGMENT-LINEAR layouts:
//   fK/gQ: [b][t=key>>4][chunk=(ch>>3)*16+(key&15)][8]  (tile = 512 shorts)
//   hT:    [b][ch>>4][key>>5][chunk=((key&31)>>3)*16+(ch&15)][8 keys]
__global__ __launch_bounds__(256) void k_proj(
    const unsigned short* __restrict__ xh,
    const unsigned short* __restrict__ xl,
    const unsigned short* __restrict__ wTh,
    const unsigned short* __restrict__ wTl,
    const float* __restrict__ bfb,
    const float* __restrict__ bgb,
    const float* __restrict__ bhb,
    unsigned short* __restrict__ fKh,
    unsigned short* __restrict__ fKl,
    unsigned short* __restrict__ gQh,
    unsigned short* __restrict__ gQl,
    unsigned short* __restrict__ hT) {
    __shared__ short sm[4 * 64 * 72];   // 36.9 KB, both paths
    int tid = threadIdx.x;
    int wave = tid >> 6, lane = tid & 63, lq = lane & 15, quad = lane >> 4;
    int rt = blockIdx.x;
    const unsigned short* xhb = xh + (size_t)rt * 64 * 256;
    const unsigned short* xlb = xl + (size_t)rt * 64 * 256;
    f32x4 zero4 = {0.f, 0.f, 0.f, 0.f};

    if (blockIdx.y < 4) {
        // h path: [64][136] X + W tiles
        const int XO = 0, WO = 64 * 136;
        int cb = blockIdx.y;
        const unsigned short* wbase = wTh + (size_t)(64 + cb * 64) * 256;
        f32x4 acc[4] = {zero4, zero4, zero4, zero4};

        for (int ph = 0; ph < 2; ++ph) {
            int k0 = ph * 128;
            __syncthreads();
#pragma unroll
            for (int u = 0; u < 4; ++u) {
                int q = u * 256 + tid;
                int row = q >> 4, kc = q & 15;
                *(short8*)&sm[XO + row * 136 + kc * 8] =
                    *(const short8*)&xhb[row * 256 + k0 + kc * 8];
                *(short8*)&sm[WO + row * 136 + kc * 8] =
                    *(const short8*)&wbase[row * 256 + k0 + kc * 8];
            }
            __syncthreads();
#pragma unroll
            for (int ks = 0; ks < 4; ++ks) {
                short8 a = *(const short8*)&sm[XO + (wave * 16 + lq) * 136 + ks * 32 + quad * 8];
#pragma unroll
                for (int ct = 0; ct < 4; ++ct) {
                    short8 bfr = *(const short8*)&sm[WO + (lq + 16 * ct) * 136 + ks * 32 + quad * 8];
                    acc[ct] = __builtin_amdgcn_mfma_f32_16x16x32_bf16(a, bfr, acc[ct], 0, 0, 0);
                }
            }
        }

        int rowl = wave * 16 + quad * 4;
        int grow0 = rt * 64;
        int bidx = grow0 >> 12, n0 = (grow0 & 4095) + rowl;
#pragma unroll
        for (int ct = 0; ct < 4; ++ct) {
            int c = cb * 64 + lq + 16 * ct;
            float bias = bhb[c];
            short4_t pk;
#pragma unroll
            for (int r = 0; r < 4; ++r) pk[r] = (short)f2bf(acc[ct][r] + bias);
            size_t a8 = (((size_t)(bidx * 16 + (c >> 4)) * 128 + (n0 >> 5)) * 64 +
                         ((n0 & 31) >> 3) * 16 + (c & 15)) * 8 + (n0 & 7);
            *(short4_t*)&hT[a8] = pk;
        }
    } else {
        // f,g path (3-term hi/lo), [64][72] tiles
        const int XH = 0, XL = 64 * 72, WH = 2 * 64 * 72, WL = 3 * 64 * 72;
        f32x4 acc[4] = {zero4, zero4, zero4, zero4};

        for (int ph = 0; ph < 4; ++ph) {
            int k0 = ph * 64;
            __syncthreads();
#pragma unroll
            for (int u = 0; u < 2; ++u) {
                int q = u * 256 + tid;
                int row = q >> 3, kc = q & 7;
                *(short8*)&sm[XH + row * 72 + kc * 8] =
                    *(const short8*)&xhb[row * 256 + k0 + kc * 8];
                *(short8*)&sm[XL + row * 72 + kc * 8] =
                    *(const short8*)&xlb[row * 256 + k0 + kc * 8];
                *(short8*)&sm[WH + row * 72 + kc * 8] =
                    *(const short8*)&wTh[row * 256 + k0 + kc * 8];
                *(short8*)&sm[WL + row * 72 + kc * 8] =
                    *(const short8*)&wTl[row * 256 + k0 + kc * 8];
            }
            __syncthreads();
#pragma unroll
            for (int ks = 0; ks < 2; ++ks) {
                short8 ah = *(const short8*)&sm[XH + (wave * 16 + lq) * 72 + ks * 32 + quad * 8];
                short8 al = *(const short8*)&sm[XL + (wave * 16 + lq) * 72 + ks * 32 + quad * 8];
#pragma unroll
                for (int ct = 0; ct < 4; ++ct) {
                    short8 bh = *(const short8*)&sm[WH + (lq + 16 * ct) * 72 + ks * 32 + quad * 8];
                    short8 bl = *(const short8*)&sm[WL + (lq + 16 * ct) * 72 + ks * 32 + quad * 8];
                    acc[ct] = __builtin_amdgcn_mfma_f32_16x16x32_bf16(ah, bh, acc[ct], 0, 0, 0);
                    acc[ct] = __builtin_amdgcn_mfma_f32_16x16x32_bf16(al, bh, acc[ct], 0, 0, 0);
                    acc[ct] = __builtin_amdgcn_mfma_f32_16x16x32_bf16(ah, bl, acc[ct], 0, 0, 0);
                }
            }
        }

        int rowl = wave * 16 + quad * 4;
#pragma unroll
        for (int ct = 0; ct < 4; ++ct) {
            int coll = lq + 16 * ct;
#pragma unroll
            for (int r = 0; r < 4; ++r) {
                int grow = rt * 64 + rowl + r;
                int bidx = grow >> 12, n = grow & 4095;
                float v = acc[ct][r];
                size_t o = (size_t)(bidx * 256 + (n >> 4)) * 512 +
                           (((coll & 31) >> 3) * 16 + (n & 15)) * 8 + (coll & 7);
                if (coll < 32) {
                    v += bfb[coll];
                    unsigned short h = f2bf(v);
                    fKh[o] = h;
                    fKl[o] = f2bf(v - bf2f(h));
                } else {
                    int cg = coll - 32;
                    size_t og = (size_t)(bidx * 256 + (n >> 4)) * 512 +
                                ((cg >> 3) * 16 + (n & 15)) * 8 + (cg & 7);
                    v += bgb[cg];
                    unsigned short h = f2bf(v);
                    gQh[og] = h;
                    gQl[og] = f2bf(v - bf2f(h));
                }
            }
        }
    }
}

// ---------------- kernel C: flash attention (no-split, fused epilogue) -----
// Grid 512 x 512 thr -> (b = bid&3 [XCD affinity], qt = bid>>2 [32-row q
// tile, 0..127]). Full 4096-key range per block (64 kts of 64 keys), so the
// softmax denominator completes in-kernel: epilogue does /l, *gamma, +x and
// writes final out. 8 waves: S wave (rs=w>>2 row-strip, kt4=w&3 key-tile)
// computes ONE 16x16 S tile (3 hi/lo MFMA); PV wave owns 32 channels
// (2ct x 2rb x 2kk = 8 MFMA). 2 blocks/CU x 8 waves = 16 waves/CU.
#define PSTR 72
__global__ __launch_bounds__(512, 4) void k_attn(
    const unsigned short* __restrict__ fKh,
    const unsigned short* __restrict__ fKl,
    const unsigned short* __restrict__ gQh,
    const unsigned short* __restrict__ gQl,
    const unsigned short* __restrict__ hT,
    const float* __restrict__ x,
    const float* __restrict__ gam_p,
    float* __restrict__ out) {
    __shared__ short Ps[2][32 * PSTR];   // 9.2 KB dbuf P (32x64 pad 72)
    __shared__ short Fb[2][2][2048];     // 16 KB dbuf f hi/lo (64x32 frag-linear)
    __shared__ float Lred[2][16][4];     // 512 B  l cross-wave reduce
    int tid = threadIdx.x;
    int wave = tid >> 6, lane = tid & 63, lq = lane & 15, quad = lane >> 4;
    int b = blockIdx.x & 3;
    int qt = blockIdx.x >> 2;            // 0..127
    int rs = wave >> 2;                  // row-strip 0/1 (16 rows)
    int kt4 = wave & 3;                  // S key-tile 0..3

    const unsigned short* fhB = fKh + (size_t)b * 131072;
    const unsigned short* flB = fKl + (size_t)b * 131072;
    const unsigned short* hB  = hT + (size_t)b * 1048576;
    int lchunk = quad * 16 + lq;         // fragment chunk index for this lane

    f32x4 zero4 = {0.f, 0.f, 0.f, 0.f};
    f32x4 acc[4];                        // [rb(2)][ct(2)]
#pragma unroll
    for (int i = 0; i < 4; ++i) acc[i] = zero4;
    float l_part[4] = {0.f, 0.f, 0.f, 0.f};

    // g A-frags: row-tile of this wave's strip
    int gtile = b * 256 + qt * 2 + rs;
    short8 ghfrag = *(const short8*)&gQh[(size_t)gtile * 512 + lchunk * 8];
    short8 glfrag = *(const short8*)&gQl[(size_t)gtile * 512 + lchunk * 8];

    // f staging: waves 0-3 stage hi, waves 4-7 stage lo (wave-uniform split)
    int sid = tid & 255;
    int hl = tid >> 8;
    const unsigned short* fB0 = hl ? flB : fhB;

    // prologue: stage f(kt=0): 4 tiles = 2048 shorts per buf, linear copy
    *(short8*)&Fb[0][hl][sid * 8] = *(const short8*)&fB0[(size_t)sid * 8];
    __syncthreads();

    for (int kt = 0; kt < 64; ++kt) {
        int p = kt & 1;
        // ---- next-f prefetch (linear, into regs) ----
        int nkt = kt < 63 ? kt + 1 : kt;
        short8 fn = *(const short8*)&fB0[(size_t)nkt * 2048 + sid * 8];

        // ---- hT B-frags: coalesced 1KB tile loads, unique per wave ----
        int k0 = kt * 2;                 // key-group (32 keys) base
        short8 hb[2][2];
#pragma unroll
        for (int ct = 0; ct < 2; ++ct) {
            int ctile = wave * 2 + ct;
#pragma unroll
            for (int kk = 0; kk < 2; ++kk)
                hb[ct][kk] = *(const short8*)
                    &hB[(((size_t)ctile * 128 + k0 + kk) * 64 + lchunk) * 8];
        }

        // ---- S = g.f^T (3-term hi/lo), ONE 16x16 tile per wave ----
        short8 fh = *(const short8*)&Fb[p][0][kt4 * 512 + lchunk * 8];
        short8 fl = *(const short8*)&Fb[p][1][kt4 * 512 + lchunk * 8];
        __builtin_amdgcn_s_setprio(1);
        f32x4 S = __builtin_amdgcn_mfma_f32_16x16x32_bf16(ghfrag, fh, zero4, 0, 0, 0);
        S = __builtin_amdgcn_mfma_f32_16x16x32_bf16(glfrag, fh, S, 0, 0, 0);
        S = __builtin_amdgcn_mfma_f32_16x16x32_bf16(ghfrag, fl, S, 0, 0, 0);
        __builtin_amdgcn_s_setprio(0);

        // ---- P = exp(S), per-lane l ----
#pragma unroll
        for (int r = 0; r < 4; ++r) {
            S[r] = __expf(S[r]);
            l_part[r] += S[r];
        }

        // ---- P (bf16) to LDS ----
#pragma unroll
        for (int r = 0; r < 4; ++r)
            Ps[p][(rs * 16 + quad * 4 + r) * PSTR + kt4 * 16 + lq] =
                (short)f2bf(S[r]);

        // ---- stage next f ----
        *(short8*)&Fb[1 - p][hl][sid * 8] = fn;

        __syncthreads();   // P[p] + Fb[1-p] visible; single barrier per kt

        // ---- PV: all 32 rows x this wave's 32 channels ----
        __builtin_amdgcn_s_setprio(1);
#pragma unroll
        for (int rb = 0; rb < 2; ++rb) {
            short8 pa0 = *(const short8*)&Ps[p][(rb * 16 + lq) * PSTR + quad * 8];
            short8 pa1 = *(const short8*)&Ps[p][(rb * 16 + lq) * PSTR + 32 + quad * 8];
#pragma unroll
            for (int ct = 0; ct < 2; ++ct) {
                acc[rb * 2 + ct] = __builtin_amdgcn_mfma_f32_16x16x32_bf16(pa0, hb[ct][0], acc[rb * 2 + ct], 0, 0, 0);
                acc[rb * 2 + ct] = __builtin_amdgcn_mfma_f32_16x16x32_bf16(pa1, hb[ct][1], acc[rb * 2 + ct], 0, 0, 0);
            }
        }
        __builtin_amdgcn_s_setprio(0);
    }

    // ---- epilogue: reduce l (lq lanes, then across the 4 key-tile waves) --
#pragma unroll
    for (int r = 0; r < 4; ++r) {
        float s = l_part[r];
        s += __shfl_xor(s, 1);
        s += __shfl_xor(s, 2);
        s += __shfl_xor(s, 4);
        s += __shfl_xor(s, 8);
        if (lq == 0) Lred[rs][quad * 4 + r][kt4] = s;
    }
    __syncthreads();

    float gam = gam_p[0];
#pragma unroll
    for (int rb = 0; rb < 2; ++rb)
#pragma unroll
        for (int r = 0; r < 4; ++r) {
            float l = Lred[rb][quad * 4 + r][0] + Lred[rb][quad * 4 + r][1] +
                      Lred[rb][quad * 4 + r][2] + Lred[rb][quad * 4 + r][3];
            float linv = 1.0f / l;
            int n = qt * 32 + rb * 16 + quad * 4 + r;
            size_t rowo = ((size_t)(b * 4096 + n)) * 256;
#pragma unroll
            for (int ct = 0; ct < 2; ++ct) {
                int c = wave * 32 + ct * 16 + lq;
                out[rowo + c] = gam * (acc[rb * 2 + ct][r] * linv) + x[rowo + c];
            }
        }
}

extern "C" void kernel_launch(void* const* d_in, const int* in_sizes, int n_in,
                              void* d_out, int out_size, void* d_ws, size_t ws_size,
                              hipStream_t stream) {
    const float* x   = (const float*)d_in[0];
    const float* Wf  = (const float*)d_in[1];
    const float* bfb = (const float*)d_in[2];
    const float* Wg  = (const float*)d_in[3];
    const float* bgb = (const float*)d_in[4];
    const float* Wh  = (const float*)d_in[5];
    const float* bhb = (const float*)d_in[6];
    const float* gam = (const float*)d_in[7];
    float* out = (float*)d_out;

    char* ws = (char*)d_ws;
    const size_t MI = 1u << 20;
    unsigned short* xh  = (unsigned short*)(ws);                  // 8 MiB
    unsigned short* xl  = (unsigned short*)(ws + 8 * MI);         // 8 MiB
    unsigned short* fKh = (unsigned short*)(ws + 16 * MI);        // 1 MiB
    unsigned short* fKl = (unsigned short*)(ws + 17 * MI);        // 1 MiB
    unsigned short* gQh = (unsigned short*)(ws + 18 * MI);        // 1 MiB
    unsigned short* gQl = (unsigned short*)(ws + 19 * MI);        // 1 MiB
    unsigned short* hT  = (unsigned short*)(ws + 20 * MI);        // 8 MiB
    unsigned short* wTh = (unsigned short*)(ws + 28 * MI);        // 160 KiB
    unsigned short* wTl = (unsigned short*)(ws + 28 * MI + 160 * 1024); // 32 KiB

    k_pre<<<dim3(2368), dim3(256), 0, stream>>>(x, Wf, Wg, Wh, xh, xl, wTh, wTl);
    k_proj<<<dim3(256, 5), dim3(256), 0, stream>>>(xh, xl, wTh, wTl, bfb, bgb, bhb,
                                                   fKh, fKl, gQh, gQl, hT);
    k_attn<<<dim3(512), dim3(512), 0, stream>>>(fKh, fKl, gQh, gQl, hT,
                                                x, gam, out);
}